// Round 11
// baseline (100.895 us; speedup 1.0000x reference)
//
#include <hip/hip_runtime.h>

#define BATCH 8
#define NPTS 4096
#define KSEL 5          // K_NN; self-candidate excluded in-scan
#define ALPHA 1.05f
#define NSEG 16         // waves per block
#define TPB (NSEG * 64)        // 1024 threads
#define PPB 128         // points per block (2 per lane)
#define HALF 2048              // candidates per half-block (fast path)
#define HSEGLEN (HALF / NSEG)  // 128 candidates per wave
#define SEGLEN (NPTS / NSEG)   // 256 (fallback kernel)

// ---------------------------------------------------------------------------
// f32 3-input min/med/max (single VOP3 instr each). Selection runs in FLOAT
// domain (g-scores can be negative). No NaNs present.
// ---------------------------------------------------------------------------
static __device__ __forceinline__ float min3f(float a, float b, float c) {
  float d;
  asm("v_min3_f32 %0, %1, %2, %3" : "=v"(d) : "v"(a), "v"(b), "v"(c));
  return d;
}
static __device__ __forceinline__ float med3f(float a, float b, float c) {
  float d;
  asm("v_med3_f32 %0, %1, %2, %3" : "=v"(d) : "v"(a), "v"(b), "v"(c));
  return d;
}
static __device__ __forceinline__ float max3f(float a, float b, float c) {
  float d;
  asm("v_max3_f32 %0, %1, %2, %3" : "=v"(d) : "v"(a), "v"(b), "v"(c));
  return d;
}

typedef float f16v __attribute__((ext_vector_type(16)));  // one 64B packed group

// Fused branchless insert of two candidates into sorted m[0..KSEL-1], float.
// 13 ops / 2 candidates — count-optimal for exact streaming top-5.
static __device__ __forceinline__ void insert2f(float m[KSEL], float tA, float tB) {
#pragma unroll
  for (int k = 0; k < KSEL - 1; ++k) {
    const float mk = m[k];
    m[k] = min3f(mk, tA, tB);
    const float nA = med3f(mk, tA, tB);
    const float nB = max3f(mk, tA, tB);
    tA = nA;
    tB = nB;
  }
  m[KSEL - 1] = min3f(m[KSEL - 1], tA, tB);
}

// ---------------------------------------------------------------------------
// R10 post-mortem: all-scalar 3-fma dist confirmed (busy 61->70%, dur -3.6us)
// but issue rate stuck at 0.74 instr/cyc: grid 256 = 1 block/CU = 4 waves/
// SIMD can't cover dependency + ds-wait bubbles (R4's 94% ran 8 waves/SIMD).
// R11: SAME per-CU totals (82k VALU instr, 4096 ds_read_b128), DOUBLE the
// waves: 512 blocks (b x tile x candidate-half), each staging its 2048-pt
// half (32KB; union w/ 40KB merge buf -> 2 blocks/CU = 80KB LDS, 2048 thr).
// __launch_bounds__(TPB, 8) pins VGPR<=64 so 8 waves/SIMD materialize.
// Partial top-5 per (point, half) -> workspace; half-merge fused into stats.
// ---------------------------------------------------------------------------
template <bool EXCL>
static __device__ __forceinline__ void knn_group4_sc(const f16v c, const int jb,
                                                     const int i0, const int i1,
                                                     const float x20, const float y20, const float z20,
                                                     const float x21, const float y21, const float z21,
                                                     float m0[KSEL], float m1[KSEL]) {
  // layout: c[0..3]=x, c[4..7]=y, c[8..11]=z, c[12..15]=r
  float g0[4], g1[4];
#pragma unroll
  for (int t = 0; t < 4; ++t) {
    const float xj = c[t], yj = c[4 + t], zj = c[8 + t], rj = c[12 + t];
    g0[t] = fmaf(xj, x20, fmaf(yj, y20, fmaf(zj, z20, rj)));
    g1[t] = fmaf(xj, x21, fmaf(yj, y21, fmaf(zj, z21, rj)));
  }
  if (EXCL) {
#pragma unroll
    for (int t = 0; t < 4; ++t) {
      if (jb + t == i0) g0[t] = __builtin_inff();
      if (jb + t == i1) g1[t] = __builtin_inff();
    }
  }
  insert2f(m0, g0[0], g0[1]);
  insert2f(m0, g0[2], g0[3]);
  insert2f(m1, g1[0], g1[1]);
  insert2f(m1, g1[2], g1[3]);
}

template <bool EXCL>
static __device__ __forceinline__ void scan_half(const f16v* __restrict__ sg,
                                                 const int gbase, const int jb0,
                                                 const int i0, const int i1,
                                                 const float x20, const float y20, const float z20,
                                                 const float x21, const float y21, const float z21,
                                                 float m0[KSEL], float m1[KSEL]) {
#pragma unroll 4
  for (int g = 0; g < HSEGLEN / 4; ++g) {   // 32 groups of 4 candidates
    const f16v c = sg[gbase + g];
    knn_group4_sc<EXCL>(c, jb0 + 4 * g, i0, i1, x20, y20, z20, x21, y21, z21, m0, m1);
  }
}

// ---------------------------------------------------------------------------
// Kernel 1 (fast path): partial top-5 over one candidate half.
// grid = 512 blocks = 8 batches x 32 tiles x 2 halves; 1024 threads (16
// waves); 2 blocks/CU -> 8 waves/SIMD. Each wave scans 128 candidates for
// the tile's 128 points (2/lane). Output: part[k][b][half][point] (SoA).
// ---------------------------------------------------------------------------
__global__ __launch_bounds__(TPB, 8) void knn_half(const float* __restrict__ pc,
                                                   float* __restrict__ part,
                                                   float* __restrict__ out) {
  __shared__ union __align__(64) {
    float pk[HALF * 4];              // 512 groups x {x[4],y[4],z[4],r[4]} = 32 KB
    float cand[NSEG][PPB][KSEL];     // 40 KB (reused after scan)
  } sh;

  const int tid = threadIdx.x;
  const int pt  = tid & 63;
  const int seg = __builtin_amdgcn_readfirstlane(tid >> 6);  // wave-uniform
  const int b    = blockIdx.x >> 6;          // 64 blocks per batch
  const int rr   = blockIdx.x & 63;
  const int tile = rr >> 1;                  // 32 tiles of 128 points
  const int half = rr & 1;                   // candidate half

  if (blockIdx.x == 0 && tid == 0) out[0] = 0.0f;  // stats kernel accumulates

  const float* __restrict__ base = pc + (size_t)b * (NPTS * 3);

  // ---- Stage this half's 2048 points: 2 per thread, packed groups + r ----
#pragma unroll
  for (int k = 0; k < HALF / TPB; ++k) {
    const int pl = tid + k * TPB;            // local point 0..2047
    const int gp = half * HALF + pl;         // global point in batch
    const float x = base[gp * 3 + 0];
    const float y = base[gp * 3 + 1];
    const float z = base[gp * 3 + 2];
    float* dst = &sh.pk[(pl >> 2) * 16];
    const int s = pl & 3;
    dst[s + 0]  = x;
    dst[s + 4]  = y;
    dst[s + 8]  = z;
    dst[s + 12] = fmaf(z, z, fmaf(y, y, x * x));  // same form as stats r_i
  }

  // Own two points (may live in the OTHER half -> read straight from pc).
  const int i0 = tile * PPB + pt;
  const int i1 = i0 + 64;
  const float xi0 = base[i0 * 3 + 0], yi0 = base[i0 * 3 + 1], zi0 = base[i0 * 3 + 2];
  const float xi1 = base[i1 * 3 + 0], yi1 = base[i1 * 3 + 1], zi1 = base[i1 * 3 + 2];
  // -2*x_i is EXACT (exponent bump + sign).
  const float x20 = -2.0f * xi0, y20 = -2.0f * yi0, z20 = -2.0f * zi0;
  const float x21 = -2.0f * xi1, y21 = -2.0f * yi1, z21 = -2.0f * zi1;

  __syncthreads();

  float m0[KSEL], m1[KSEL];
#pragma unroll
  for (int k = 0; k < KSEL; ++k) { m0[k] = __builtin_inff(); m1[k] = __builtin_inff(); }

  const int jb0   = half * HALF + seg * HSEGLEN;  // global candidate base
  const int gbase = seg * (HSEGLEN / 4);
  const f16v* __restrict__ sg = (const f16v*)sh.pk;

  // The tile's 128 point indices occupy exactly one 128-candidate wave
  // segment: (half*16 + seg) == tile. Only that wave pays the compares.
  if (half * NSEG + seg == tile) {
    scan_half<true>(sg, gbase, jb0, i0, i1, x20, y20, z20, x21, y21, z21, m0, m1);
  } else {
    scan_half<false>(sg, gbase, jb0, i0, i1, x20, y20, z20, x21, y21, z21, m0, m1);
  }
  __syncthreads();  // all waves done reading the stage buffer

#pragma unroll
  for (int k = 0; k < KSEL; ++k) {
    sh.cand[seg][pt][k]      = m0[k];
    sh.cand[seg][pt + 64][k] = m1[k];
  }
  __syncthreads();

  // Tree-merge the 16 sorted lists per point: 8,4,2,1 pairwise merges.
  for (int st = 1; st < NSEG; st <<= 1) {
    const int pairs = NSEG / (2 * st);
    if (tid < pairs * PPB) {
      const int q = tid >> 7;
      const int p = tid & (PPB - 1);
      float* A = &sh.cand[2 * st * q][p][0];
      const float* B = &sh.cand[2 * st * q + st][p][0];
      float mm[KSEL];
#pragma unroll
      for (int k = 0; k < KSEL; ++k) mm[k] = A[k];
#pragma unroll
      for (int k = 0; k < KSEL; ++k) {
        float t = B[k];
#pragma unroll
        for (int u = 0; u < KSEL - 1; ++u) {
          const float lo = fminf(mm[u], t);
          t = fmaxf(mm[u], t);
          mm[u] = lo;
        }
        mm[KSEL - 1] = fminf(mm[KSEL - 1], t);
      }
#pragma unroll
      for (int k = 0; k < KSEL; ++k) A[k] = mm[k];
    }
    __syncthreads();
  }

  // Write this half's sorted partial top-5 (SoA by k for coalescing).
  if (tid < PPB) {
    const int p = tile * PPB + tid;
#pragma unroll
    for (int k = 0; k < KSEL; ++k) {
      part[(((size_t)k * BATCH + b) * 2 + half) * NPTS + p] = sh.cand[0][tid][k];
    }
  }
}

// ---------------------------------------------------------------------------
// Kernel 2 (fast path): fused half-merge + per-batch stats.
// Pass 1 merges the two sorted-5 partials per point (exact top-5 of all 4096
// candidates — same sorted values as a full tree merge), adds r_i, caches
// the value in LDS, accumulates the mean. Passes 2-3 reuse the LDS copy.
// Same accumulation order as the previous stats kernel -> bit-exact.
// ---------------------------------------------------------------------------
__global__ __launch_bounds__(256) void stats_fused(const float* __restrict__ part,
                                                   const float* __restrict__ pc,
                                                   const float* __restrict__ weights,
                                                   float* __restrict__ out) {
  __shared__ float vbuf[NPTS];   // 16 KB merged values
  __shared__ float red[256];
  const int b   = blockIdx.x;
  const int tid = threadIdx.x;

  // pass 1: merge + value + mean
  float s = 0.f;
  for (int j = tid; j < NPTS; j += 256) {
    float mm[KSEL];
#pragma unroll
    for (int k = 0; k < KSEL; ++k)
      mm[k] = part[(((size_t)k * BATCH + b) * 2 + 0) * NPTS + j];
#pragma unroll
    for (int k = 0; k < KSEL; ++k) {
      float t = part[(((size_t)k * BATCH + b) * 2 + 1) * NPTS + j];
#pragma unroll
      for (int u = 0; u < KSEL - 1; ++u) {
        const float lo = fminf(mm[u], t);
        t = fmaxf(mm[u], t);
        mm[u] = lo;
      }
      mm[KSEL - 1] = fminf(mm[KSEL - 1], t);
    }
    float s5 = 0.f;
#pragma unroll
    for (int k = 0; k < KSEL; ++k) s5 += mm[k];  // ascending sum, as before
    const float x = pc[((size_t)b * NPTS + j) * 3 + 0];
    const float y = pc[((size_t)b * NPTS + j) * 3 + 1];
    const float z = pc[((size_t)b * NPTS + j) * 3 + 2];
    const float v = s5 * 0.2f + fmaf(z, z, fmaf(y, y, x * x));
    vbuf[j] = v;
    s += v;
  }
  red[tid] = s;
  __syncthreads();
  for (int off = 128; off > 0; off >>= 1) {
    if (tid < off) red[tid] += red[tid + off];
    __syncthreads();
  }
  const float mean = red[0] * (1.0f / NPTS);
  __syncthreads();

  // pass 2: unbiased std
  float s2 = 0.f;
  for (int j = tid; j < NPTS; j += 256) {
    const float d = vbuf[j] - mean;
    s2 += d * d;
  }
  red[tid] = s2;
  __syncthreads();
  for (int off = 128; off > 0; off >>= 1) {
    if (tid < off) red[tid] += red[tid + off];
    __syncthreads();
  }
  const float thr = mean + ALPHA * sqrtf(red[0] * (1.0f / (NPTS - 1)));
  __syncthreads();

  // pass 3: masked sum (strict >)
  float s3 = 0.f;
  for (int j = tid; j < NPTS; j += 256) {
    const float vv = vbuf[j];
    if (vv > thr) s3 += vv;
  }
  red[tid] = s3;
  __syncthreads();
  for (int off = 128; off > 0; off >>= 1) {
    if (tid < off) red[tid] += red[tid + off];
    __syncthreads();
  }
  if (tid == 0) {
    atomicAdd(out, red[0] * (1.0f / NPTS) * weights[b] * (1.0f / BATCH));
  }
}

// ---------------------------------------------------------------------------
// Fallback (ws too small for part buffer): R10 kernels, unchanged.
// ---------------------------------------------------------------------------
template <bool EXCL>
static __device__ __forceinline__ void scan_seg_sc2(const f16v* __restrict__ sg,
                                                    const int g0i, const int j0,
                                                    const int i0, const int i1,
                                                    const float x20, const float y20, const float z20,
                                                    const float x21, const float y21, const float z21,
                                                    float m0[KSEL], float m1[KSEL]) {
#pragma unroll 4
  for (int g = 0; g < SEGLEN / 4; ++g) {
    const f16v c = sg[g0i + g];
    knn_group4_sc<EXCL>(c, j0 + 4 * g, i0, i1, x20, y20, z20, x21, y21, z21, m0, m1);
  }
}

__global__ __launch_bounds__(TPB) void knn_value_sc2(const float* __restrict__ pc,
                                                     float* __restrict__ value,
                                                     float* __restrict__ out) {
  __shared__ union __align__(64) {
    float pk[NPTS * 4];
    float cand[NSEG][PPB][KSEL];
  } sh;

  const int tid = threadIdx.x;
  const int pt  = tid & 63;
  const int seg = __builtin_amdgcn_readfirstlane(tid >> 6);
  const int b    = blockIdx.x >> 5;
  const int tile = blockIdx.x & 31;
  const int i0   = tile * PPB + pt;
  const int i1   = i0 + 64;

  if (blockIdx.x == 0 && tid == 0) out[0] = 0.0f;

  const float* __restrict__ base = pc + (size_t)b * (NPTS * 3);
#pragma unroll
  for (int k = 0; k < NPTS / TPB; ++k) {
    const int p = tid + k * TPB;
    const float x = base[p * 3 + 0];
    const float y = base[p * 3 + 1];
    const float z = base[p * 3 + 2];
    float* dst = &sh.pk[(p >> 2) * 16];
    const int s = p & 3;
    dst[s + 0]  = x;
    dst[s + 4]  = y;
    dst[s + 8]  = z;
    dst[s + 12] = fmaf(z, z, fmaf(y, y, x * x));
  }
  __syncthreads();

  const int gi0 = (i0 >> 2) * 16 + (i0 & 3);
  const int gi1 = (i1 >> 2) * 16 + (i1 & 3);
  const float xi0 = sh.pk[gi0 + 0], yi0 = sh.pk[gi0 + 4], zi0 = sh.pk[gi0 + 8];
  const float xi1 = sh.pk[gi1 + 0], yi1 = sh.pk[gi1 + 4], zi1 = sh.pk[gi1 + 8];
  const float x20 = -2.0f * xi0, y20 = -2.0f * yi0, z20 = -2.0f * zi0;
  const float x21 = -2.0f * xi1, y21 = -2.0f * yi1, z21 = -2.0f * zi1;

  float m0[KSEL], m1[KSEL];
#pragma unroll
  for (int k = 0; k < KSEL; ++k) { m0[k] = __builtin_inff(); m1[k] = __builtin_inff(); }

  const int j0  = seg * SEGLEN;
  const int g0i = seg * (SEGLEN / 4);
  const f16v* __restrict__ sg = (const f16v*)sh.pk;

  if (seg == (tile >> 1)) {
    scan_seg_sc2<true>(sg, g0i, j0, i0, i1, x20, y20, z20, x21, y21, z21, m0, m1);
  } else {
    scan_seg_sc2<false>(sg, g0i, j0, i0, i1, x20, y20, z20, x21, y21, z21, m0, m1);
  }
  __syncthreads();

#pragma unroll
  for (int k = 0; k < KSEL; ++k) {
    sh.cand[seg][pt][k]      = m0[k];
    sh.cand[seg][pt + 64][k] = m1[k];
  }
  __syncthreads();

  for (int st = 1; st < NSEG; st <<= 1) {
    const int pairs = NSEG / (2 * st);
    if (tid < pairs * PPB) {
      const int q = tid >> 7;
      const int p = tid & (PPB - 1);
      float* A = &sh.cand[2 * st * q][p][0];
      const float* B = &sh.cand[2 * st * q + st][p][0];
      float mm[KSEL];
#pragma unroll
      for (int k = 0; k < KSEL; ++k) mm[k] = A[k];
#pragma unroll
      for (int k = 0; k < KSEL; ++k) {
        float t = B[k];
#pragma unroll
        for (int u = 0; u < KSEL - 1; ++u) {
          const float lo = fminf(mm[u], t);
          t = fmaxf(mm[u], t);
          mm[u] = lo;
        }
        mm[KSEL - 1] = fminf(mm[KSEL - 1], t);
      }
#pragma unroll
      for (int k = 0; k < KSEL; ++k) A[k] = mm[k];
    }
    __syncthreads();
  }

  if (tid < PPB) {
    float s5 = 0.f;
#pragma unroll
    for (int k = 0; k < KSEL; ++k) s5 += sh.cand[0][tid][k];
    float xx, yy, zz;
    if (tid < 64) { xx = xi0; yy = yi0; zz = zi0; }
    else          { xx = xi1; yy = yi1; zz = zi1; }
    const float ri = fmaf(zz, zz, fmaf(yy, yy, xx * xx));
    value[b * NPTS + tile * PPB + tid] = s5 * 0.2f + ri;
  }
}

__global__ __launch_bounds__(256) void stats_kernel(const float* __restrict__ value,
                                                    const float* __restrict__ weights,
                                                    float* __restrict__ out) {
  __shared__ float red[256];
  const int b   = blockIdx.x;
  const int tid = threadIdx.x;
  const float* __restrict__ v = value + b * NPTS;

  float s = 0.f;
  for (int j = tid; j < NPTS; j += 256) s += v[j];
  red[tid] = s;
  __syncthreads();
  for (int off = 128; off > 0; off >>= 1) {
    if (tid < off) red[tid] += red[tid + off];
    __syncthreads();
  }
  const float mean = red[0] * (1.0f / NPTS);
  __syncthreads();

  float s2 = 0.f;
  for (int j = tid; j < NPTS; j += 256) {
    const float d = v[j] - mean;
    s2 += d * d;
  }
  red[tid] = s2;
  __syncthreads();
  for (int off = 128; off > 0; off >>= 1) {
    if (tid < off) red[tid] += red[tid + off];
    __syncthreads();
  }
  const float thr = mean + ALPHA * sqrtf(red[0] * (1.0f / (NPTS - 1)));
  __syncthreads();

  float s3 = 0.f;
  for (int j = tid; j < NPTS; j += 256) {
    const float vv = v[j];
    if (vv > thr) s3 += vv;
  }
  red[tid] = s3;
  __syncthreads();
  for (int off = 128; off > 0; off >>= 1) {
    if (tid < off) red[tid] += red[tid + off];
    __syncthreads();
  }
  if (tid == 0) {
    atomicAdd(out, red[0] * (1.0f / NPTS) * weights[b] * (1.0f / BATCH));
  }
}

extern "C" void kernel_launch(void* const* d_in, const int* in_sizes, int n_in,
                              void* d_out, int out_size, void* d_ws, size_t ws_size,
                              hipStream_t stream) {
  const float* pc      = (const float*)d_in[0];   // [8,4096,3] f32
  const float* weights = (const float*)d_in[1];   // [8] f32
  float* out   = (float*)d_out;                   // scalar f32
  float* wsf   = (float*)d_ws;

  const size_t NB    = (size_t)BATCH * NPTS;                  // 32768
  const size_t partf = (size_t)KSEL * BATCH * 2 * NPTS;       // 327680 floats
  const size_t need  = partf * sizeof(float);                 // 1.31 MB

  if (ws_size >= need) {
    float* part = wsf;
    knn_half<<<dim3(BATCH * 64), dim3(TPB), 0, stream>>>(pc, part, out);
    stats_fused<<<dim3(BATCH), dim3(256), 0, stream>>>(part, pc, weights, out);
  } else {
    float* value = wsf;                           // 128 KB (R10 layout)
    knn_value_sc2<<<dim3(BATCH * (NPTS / PPB)), dim3(TPB), 0, stream>>>(pc, value, out);
    stats_kernel<<<dim3(BATCH), dim3(256), 0, stream>>>(value, weights, out);
  }
}

// Round 12
// 94.458 us; speedup vs baseline: 1.0681x; 1.0681x over previous
//
#include <hip/hip_runtime.h>

#define BATCH 8
#define NPTS 4096
#define KSEL 5          // K_NN; self-candidate excluded in-scan
#define ALPHA 1.05f
#define NSEG 16         // waves per block
#define TPB (NSEG * 64)        // 1024 threads
#define PPB 128         // points per block (2 per lane)
#define HALF 2048              // candidates per half-block (fast path)
#define HSEGLEN (HALF / NSEG)  // 128 candidates per wave
#define SEGLEN (NPTS / NSEG)   // 256 (fallback kernel)
#define STATS_T 1024           // stats block size (R11 was 256: 1 wave/SIMD, latency-bound)

// ---------------------------------------------------------------------------
// f32 3-input min/med/max (single VOP3 instr each). Selection runs in FLOAT
// domain (g-scores can be negative). No NaNs present.
// ---------------------------------------------------------------------------
static __device__ __forceinline__ float min3f(float a, float b, float c) {
  float d;
  asm("v_min3_f32 %0, %1, %2, %3" : "=v"(d) : "v"(a), "v"(b), "v"(c));
  return d;
}
static __device__ __forceinline__ float med3f(float a, float b, float c) {
  float d;
  asm("v_med3_f32 %0, %1, %2, %3" : "=v"(d) : "v"(a), "v"(b), "v"(c));
  return d;
}
static __device__ __forceinline__ float max3f(float a, float b, float c) {
  float d;
  asm("v_max3_f32 %0, %1, %2, %3" : "=v"(d) : "v"(a), "v"(b), "v"(c));
  return d;
}

typedef float f16v __attribute__((ext_vector_type(16)));  // one 64B packed group

// Fused branchless insert of two candidates into sorted m[0..KSEL-1], float.
// 13 ops / 2 candidates — count-optimal for exact streaming top-5.
static __device__ __forceinline__ void insert2f(float m[KSEL], float tA, float tB) {
#pragma unroll
  for (int k = 0; k < KSEL - 1; ++k) {
    const float mk = m[k];
    m[k] = min3f(mk, tA, tB);
    const float nA = med3f(mk, tA, tB);
    const float nB = max3f(mk, tA, tB);
    tA = nA;
    tB = nB;
  }
  m[KSEL - 1] = min3f(m[KSEL - 1], tA, tB);
}

// ---------------------------------------------------------------------------
// R11 post-mortem: 8 waves/SIMD confirmed (busy 70->77.7%, issue 0.74->0.82,
// knn 46->41.9us) but stats_fused ran 8 blocks x 256 thr = 1 wave/SIMD on 8
// CUs pulling 1.7MB -> ~9us latency-bound, eating the win. R12: stats at
// 1024 threads (4 waves/SIMD); scan unroll 4->8 (32 b128 in flight,
// launch_bounds caps VGPR<=64 so 8 waves/SIMD survive).
// ---------------------------------------------------------------------------
template <bool EXCL>
static __device__ __forceinline__ void knn_group4_sc(const f16v c, const int jb,
                                                     const int i0, const int i1,
                                                     const float x20, const float y20, const float z20,
                                                     const float x21, const float y21, const float z21,
                                                     float m0[KSEL], float m1[KSEL]) {
  // layout: c[0..3]=x, c[4..7]=y, c[8..11]=z, c[12..15]=r
  float g0[4], g1[4];
#pragma unroll
  for (int t = 0; t < 4; ++t) {
    const float xj = c[t], yj = c[4 + t], zj = c[8 + t], rj = c[12 + t];
    g0[t] = fmaf(xj, x20, fmaf(yj, y20, fmaf(zj, z20, rj)));
    g1[t] = fmaf(xj, x21, fmaf(yj, y21, fmaf(zj, z21, rj)));
  }
  if (EXCL) {
#pragma unroll
    for (int t = 0; t < 4; ++t) {
      if (jb + t == i0) g0[t] = __builtin_inff();
      if (jb + t == i1) g1[t] = __builtin_inff();
    }
  }
  insert2f(m0, g0[0], g0[1]);
  insert2f(m0, g0[2], g0[3]);
  insert2f(m1, g1[0], g1[1]);
  insert2f(m1, g1[2], g1[3]);
}

template <bool EXCL>
static __device__ __forceinline__ void scan_half(const f16v* __restrict__ sg,
                                                 const int gbase, const int jb0,
                                                 const int i0, const int i1,
                                                 const float x20, const float y20, const float z20,
                                                 const float x21, const float y21, const float z21,
                                                 float m0[KSEL], float m1[KSEL]) {
#pragma unroll 8
  for (int g = 0; g < HSEGLEN / 4; ++g) {   // 32 groups of 4 candidates
    const f16v c = sg[gbase + g];
    knn_group4_sc<EXCL>(c, jb0 + 4 * g, i0, i1, x20, y20, z20, x21, y21, z21, m0, m1);
  }
}

// ---------------------------------------------------------------------------
// Kernel 1 (fast path): partial top-5 over one candidate half.
// grid = 512 blocks = 8 batches x 32 tiles x 2 halves; 1024 threads (16
// waves); 2 blocks/CU -> 8 waves/SIMD. Each wave scans 128 candidates for
// the tile's 128 points (2/lane). Output: part[k][b][half][point] (SoA).
// ---------------------------------------------------------------------------
__global__ __launch_bounds__(TPB, 8) void knn_half(const float* __restrict__ pc,
                                                   float* __restrict__ part,
                                                   float* __restrict__ out) {
  __shared__ union __align__(64) {
    float pk[HALF * 4];              // 512 groups x {x[4],y[4],z[4],r[4]} = 32 KB
    float cand[NSEG][PPB][KSEL];     // 40 KB (reused after scan)
  } sh;

  const int tid = threadIdx.x;
  const int pt  = tid & 63;
  const int seg = __builtin_amdgcn_readfirstlane(tid >> 6);  // wave-uniform
  const int b    = blockIdx.x >> 6;          // 64 blocks per batch
  const int rr   = blockIdx.x & 63;
  const int tile = rr >> 1;                  // 32 tiles of 128 points
  const int half = rr & 1;                   // candidate half

  if (blockIdx.x == 0 && tid == 0) out[0] = 0.0f;  // stats kernel accumulates

  const float* __restrict__ base = pc + (size_t)b * (NPTS * 3);

  // ---- Stage this half's 2048 points: 2 per thread, packed groups + r ----
#pragma unroll
  for (int k = 0; k < HALF / TPB; ++k) {
    const int pl = tid + k * TPB;            // local point 0..2047
    const int gp = half * HALF + pl;         // global point in batch
    const float x = base[gp * 3 + 0];
    const float y = base[gp * 3 + 1];
    const float z = base[gp * 3 + 2];
    float* dst = &sh.pk[(pl >> 2) * 16];
    const int s = pl & 3;
    dst[s + 0]  = x;
    dst[s + 4]  = y;
    dst[s + 8]  = z;
    dst[s + 12] = fmaf(z, z, fmaf(y, y, x * x));  // same form as stats r_i
  }

  // Own two points (may live in the OTHER half -> read straight from pc).
  const int i0 = tile * PPB + pt;
  const int i1 = i0 + 64;
  const float xi0 = base[i0 * 3 + 0], yi0 = base[i0 * 3 + 1], zi0 = base[i0 * 3 + 2];
  const float xi1 = base[i1 * 3 + 0], yi1 = base[i1 * 3 + 1], zi1 = base[i1 * 3 + 2];
  // -2*x_i is EXACT (exponent bump + sign).
  const float x20 = -2.0f * xi0, y20 = -2.0f * yi0, z20 = -2.0f * zi0;
  const float x21 = -2.0f * xi1, y21 = -2.0f * yi1, z21 = -2.0f * zi1;

  __syncthreads();

  float m0[KSEL], m1[KSEL];
#pragma unroll
  for (int k = 0; k < KSEL; ++k) { m0[k] = __builtin_inff(); m1[k] = __builtin_inff(); }

  const int jb0   = half * HALF + seg * HSEGLEN;  // global candidate base
  const int gbase = seg * (HSEGLEN / 4);
  const f16v* __restrict__ sg = (const f16v*)sh.pk;

  // The tile's 128 point indices occupy exactly one 128-candidate wave
  // segment: (half*16 + seg) == tile. Only that wave pays the compares.
  if (half * NSEG + seg == tile) {
    scan_half<true>(sg, gbase, jb0, i0, i1, x20, y20, z20, x21, y21, z21, m0, m1);
  } else {
    scan_half<false>(sg, gbase, jb0, i0, i1, x20, y20, z20, x21, y21, z21, m0, m1);
  }
  __syncthreads();  // all waves done reading the stage buffer

#pragma unroll
  for (int k = 0; k < KSEL; ++k) {
    sh.cand[seg][pt][k]      = m0[k];
    sh.cand[seg][pt + 64][k] = m1[k];
  }
  __syncthreads();

  // Tree-merge the 16 sorted lists per point: 8,4,2,1 pairwise merges.
  for (int st = 1; st < NSEG; st <<= 1) {
    const int pairs = NSEG / (2 * st);
    if (tid < pairs * PPB) {
      const int q = tid >> 7;
      const int p = tid & (PPB - 1);
      float* A = &sh.cand[2 * st * q][p][0];
      const float* B = &sh.cand[2 * st * q + st][p][0];
      float mm[KSEL];
#pragma unroll
      for (int k = 0; k < KSEL; ++k) mm[k] = A[k];
#pragma unroll
      for (int k = 0; k < KSEL; ++k) {
        float t = B[k];
#pragma unroll
        for (int u = 0; u < KSEL - 1; ++u) {
          const float lo = fminf(mm[u], t);
          t = fmaxf(mm[u], t);
          mm[u] = lo;
        }
        mm[KSEL - 1] = fminf(mm[KSEL - 1], t);
      }
#pragma unroll
      for (int k = 0; k < KSEL; ++k) A[k] = mm[k];
    }
    __syncthreads();
  }

  // Write this half's sorted partial top-5 (SoA by k for coalescing).
  if (tid < PPB) {
    const int p = tile * PPB + tid;
#pragma unroll
    for (int k = 0; k < KSEL; ++k) {
      part[(((size_t)k * BATCH + b) * 2 + half) * NPTS + p] = sh.cand[0][tid][k];
    }
  }
}

// ---------------------------------------------------------------------------
// Kernel 2 (fast path): fused half-merge + per-batch stats. 1024 threads
// (4 waves/SIMD — R11's 256-thread version was 1 wave/SIMD, latency-bound).
// Pass 1 merges the two sorted-5 partials per point (exact top-5 of all 4096
// candidates), adds r_i, caches value in LDS, accumulates mean. Passes 2-3
// reuse the LDS copy.
// ---------------------------------------------------------------------------
__global__ __launch_bounds__(STATS_T) void stats_fused(const float* __restrict__ part,
                                                       const float* __restrict__ pc,
                                                       const float* __restrict__ weights,
                                                       float* __restrict__ out) {
  __shared__ float vbuf[NPTS];   // 16 KB merged values
  __shared__ float red[STATS_T];
  const int b   = blockIdx.x;
  const int tid = threadIdx.x;

  // pass 1: merge + value + mean
  float s = 0.f;
  for (int j = tid; j < NPTS; j += STATS_T) {
    float mm[KSEL];
#pragma unroll
    for (int k = 0; k < KSEL; ++k)
      mm[k] = part[(((size_t)k * BATCH + b) * 2 + 0) * NPTS + j];
#pragma unroll
    for (int k = 0; k < KSEL; ++k) {
      float t = part[(((size_t)k * BATCH + b) * 2 + 1) * NPTS + j];
#pragma unroll
      for (int u = 0; u < KSEL - 1; ++u) {
        const float lo = fminf(mm[u], t);
        t = fmaxf(mm[u], t);
        mm[u] = lo;
      }
      mm[KSEL - 1] = fminf(mm[KSEL - 1], t);
    }
    float s5 = 0.f;
#pragma unroll
    for (int k = 0; k < KSEL; ++k) s5 += mm[k];  // ascending sum, as before
    const float x = pc[((size_t)b * NPTS + j) * 3 + 0];
    const float y = pc[((size_t)b * NPTS + j) * 3 + 1];
    const float z = pc[((size_t)b * NPTS + j) * 3 + 2];
    const float v = s5 * 0.2f + fmaf(z, z, fmaf(y, y, x * x));
    vbuf[j] = v;
    s += v;
  }
  red[tid] = s;
  __syncthreads();
  for (int off = STATS_T / 2; off > 0; off >>= 1) {
    if (tid < off) red[tid] += red[tid + off];
    __syncthreads();
  }
  const float mean = red[0] * (1.0f / NPTS);
  __syncthreads();

  // pass 2: unbiased std
  float s2 = 0.f;
  for (int j = tid; j < NPTS; j += STATS_T) {
    const float d = vbuf[j] - mean;
    s2 += d * d;
  }
  red[tid] = s2;
  __syncthreads();
  for (int off = STATS_T / 2; off > 0; off >>= 1) {
    if (tid < off) red[tid] += red[tid + off];
    __syncthreads();
  }
  const float thr = mean + ALPHA * sqrtf(red[0] * (1.0f / (NPTS - 1)));
  __syncthreads();

  // pass 3: masked sum (strict >)
  float s3 = 0.f;
  for (int j = tid; j < NPTS; j += STATS_T) {
    const float vv = vbuf[j];
    if (vv > thr) s3 += vv;
  }
  red[tid] = s3;
  __syncthreads();
  for (int off = STATS_T / 2; off > 0; off >>= 1) {
    if (tid < off) red[tid] += red[tid + off];
    __syncthreads();
  }
  if (tid == 0) {
    atomicAdd(out, red[0] * (1.0f / NPTS) * weights[b] * (1.0f / BATCH));
  }
}

// ---------------------------------------------------------------------------
// Fallback (ws too small for part buffer): R10 kernels, unchanged.
// ---------------------------------------------------------------------------
template <bool EXCL>
static __device__ __forceinline__ void scan_seg_sc2(const f16v* __restrict__ sg,
                                                    const int g0i, const int j0,
                                                    const int i0, const int i1,
                                                    const float x20, const float y20, const float z20,
                                                    const float x21, const float y21, const float z21,
                                                    float m0[KSEL], float m1[KSEL]) {
#pragma unroll 4
  for (int g = 0; g < SEGLEN / 4; ++g) {
    const f16v c = sg[g0i + g];
    knn_group4_sc<EXCL>(c, j0 + 4 * g, i0, i1, x20, y20, z20, x21, y21, z21, m0, m1);
  }
}

__global__ __launch_bounds__(TPB) void knn_value_sc2(const float* __restrict__ pc,
                                                     float* __restrict__ value,
                                                     float* __restrict__ out) {
  __shared__ union __align__(64) {
    float pk[NPTS * 4];
    float cand[NSEG][PPB][KSEL];
  } sh;

  const int tid = threadIdx.x;
  const int pt  = tid & 63;
  const int seg = __builtin_amdgcn_readfirstlane(tid >> 6);
  const int b    = blockIdx.x >> 5;
  const int tile = blockIdx.x & 31;
  const int i0   = tile * PPB + pt;
  const int i1   = i0 + 64;

  if (blockIdx.x == 0 && tid == 0) out[0] = 0.0f;

  const float* __restrict__ base = pc + (size_t)b * (NPTS * 3);
#pragma unroll
  for (int k = 0; k < NPTS / TPB; ++k) {
    const int p = tid + k * TPB;
    const float x = base[p * 3 + 0];
    const float y = base[p * 3 + 1];
    const float z = base[p * 3 + 2];
    float* dst = &sh.pk[(p >> 2) * 16];
    const int s = p & 3;
    dst[s + 0]  = x;
    dst[s + 4]  = y;
    dst[s + 8]  = z;
    dst[s + 12] = fmaf(z, z, fmaf(y, y, x * x));
  }
  __syncthreads();

  const int gi0 = (i0 >> 2) * 16 + (i0 & 3);
  const int gi1 = (i1 >> 2) * 16 + (i1 & 3);
  const float xi0 = sh.pk[gi0 + 0], yi0 = sh.pk[gi0 + 4], zi0 = sh.pk[gi0 + 8];
  const float xi1 = sh.pk[gi1 + 0], yi1 = sh.pk[gi1 + 4], zi1 = sh.pk[gi1 + 8];
  const float x20 = -2.0f * xi0, y20 = -2.0f * yi0, z20 = -2.0f * zi0;
  const float x21 = -2.0f * xi1, y21 = -2.0f * yi1, z21 = -2.0f * zi1;

  float m0[KSEL], m1[KSEL];
#pragma unroll
  for (int k = 0; k < KSEL; ++k) { m0[k] = __builtin_inff(); m1[k] = __builtin_inff(); }

  const int j0  = seg * SEGLEN;
  const int g0i = seg * (SEGLEN / 4);
  const f16v* __restrict__ sg = (const f16v*)sh.pk;

  if (seg == (tile >> 1)) {
    scan_seg_sc2<true>(sg, g0i, j0, i0, i1, x20, y20, z20, x21, y21, z21, m0, m1);
  } else {
    scan_seg_sc2<false>(sg, g0i, j0, i0, i1, x20, y20, z20, x21, y21, z21, m0, m1);
  }
  __syncthreads();

#pragma unroll
  for (int k = 0; k < KSEL; ++k) {
    sh.cand[seg][pt][k]      = m0[k];
    sh.cand[seg][pt + 64][k] = m1[k];
  }
  __syncthreads();

  for (int st = 1; st < NSEG; st <<= 1) {
    const int pairs = NSEG / (2 * st);
    if (tid < pairs * PPB) {
      const int q = tid >> 7;
      const int p = tid & (PPB - 1);
      float* A = &sh.cand[2 * st * q][p][0];
      const float* B = &sh.cand[2 * st * q + st][p][0];
      float mm[KSEL];
#pragma unroll
      for (int k = 0; k < KSEL; ++k) mm[k] = A[k];
#pragma unroll
      for (int k = 0; k < KSEL; ++k) {
        float t = B[k];
#pragma unroll
        for (int u = 0; u < KSEL - 1; ++u) {
          const float lo = fminf(mm[u], t);
          t = fmaxf(mm[u], t);
          mm[u] = lo;
        }
        mm[KSEL - 1] = fminf(mm[KSEL - 1], t);
      }
#pragma unroll
      for (int k = 0; k < KSEL; ++k) A[k] = mm[k];
    }
    __syncthreads();
  }

  if (tid < PPB) {
    float s5 = 0.f;
#pragma unroll
    for (int k = 0; k < KSEL; ++k) s5 += sh.cand[0][tid][k];
    float xx, yy, zz;
    if (tid < 64) { xx = xi0; yy = yi0; zz = zi0; }
    else          { xx = xi1; yy = yi1; zz = zi1; }
    const float ri = fmaf(zz, zz, fmaf(yy, yy, xx * xx));
    value[b * NPTS + tile * PPB + tid] = s5 * 0.2f + ri;
  }
}

__global__ __launch_bounds__(256) void stats_kernel(const float* __restrict__ value,
                                                    const float* __restrict__ weights,
                                                    float* __restrict__ out) {
  __shared__ float red[256];
  const int b   = blockIdx.x;
  const int tid = threadIdx.x;
  const float* __restrict__ v = value + b * NPTS;

  float s = 0.f;
  for (int j = tid; j < NPTS; j += 256) s += v[j];
  red[tid] = s;
  __syncthreads();
  for (int off = 128; off > 0; off >>= 1) {
    if (tid < off) red[tid] += red[tid + off];
    __syncthreads();
  }
  const float mean = red[0] * (1.0f / NPTS);
  __syncthreads();

  float s2 = 0.f;
  for (int j = tid; j < NPTS; j += 256) {
    const float d = v[j] - mean;
    s2 += d * d;
  }
  red[tid] = s2;
  __syncthreads();
  for (int off = 128; off > 0; off >>= 1) {
    if (tid < off) red[tid] += red[tid + off];
    __syncthreads();
  }
  const float thr = mean + ALPHA * sqrtf(red[0] * (1.0f / (NPTS - 1)));
  __syncthreads();

  float s3 = 0.f;
  for (int j = tid; j < NPTS; j += 256) {
    const float vv = v[j];
    if (vv > thr) s3 += vv;
  }
  red[tid] = s3;
  __syncthreads();
  for (int off = 128; off > 0; off >>= 1) {
    if (tid < off) red[tid] += red[tid + off];
    __syncthreads();
  }
  if (tid == 0) {
    atomicAdd(out, red[0] * (1.0f / NPTS) * weights[b] * (1.0f / BATCH));
  }
}

extern "C" void kernel_launch(void* const* d_in, const int* in_sizes, int n_in,
                              void* d_out, int out_size, void* d_ws, size_t ws_size,
                              hipStream_t stream) {
  const float* pc      = (const float*)d_in[0];   // [8,4096,3] f32
  const float* weights = (const float*)d_in[1];   // [8] f32
  float* out   = (float*)d_out;                   // scalar f32
  float* wsf   = (float*)d_ws;

  const size_t partf = (size_t)KSEL * BATCH * 2 * NPTS;       // 327680 floats
  const size_t need  = partf * sizeof(float);                 // 1.31 MB

  if (ws_size >= need) {
    float* part = wsf;
    knn_half<<<dim3(BATCH * 64), dim3(TPB), 0, stream>>>(pc, part, out);
    stats_fused<<<dim3(BATCH), dim3(STATS_T), 0, stream>>>(part, pc, weights, out);
  } else {
    float* value = wsf;                           // 128 KB (R10 layout)
    knn_value_sc2<<<dim3(BATCH * (NPTS / PPB)), dim3(TPB), 0, stream>>>(pc, value, out);
    stats_kernel<<<dim3(BATCH), dim3(256), 0, stream>>>(value, weights, out);
  }
}